// Round 1
// baseline (231.417 us; speedup 1.0000x reference)
//
#include <hip/hip_runtime.h>
#include <hip/hip_bf16.h>
#include <math.h>

// Problem constants (fixed by the reference file)
#define T_TOK 2048
#define H_DIM 1024
#define I_DIM 2048
#define E_NUM 8
#define TOPK  2
#define P_MAX (T_TOK * TOPK)   // 4096 (token, k) pairs
#define MAX_SLOTS 40           // sum_e ceil(M_e/128) <= 32 + 7 = 39

typedef __bf16 bf16_t;
typedef __attribute__((ext_vector_type(8))) __bf16 bf16x8;
typedef __attribute__((ext_vector_type(4))) float  f32x4;

__device__ inline f32x4 zero4() {
    f32x4 z; z[0] = 0.f; z[1] = 0.f; z[2] = 0.f; z[3] = 0.f; return z;
}

// ---------------------------------------------------------------- init
__global__ void init_kernel(int* counts, int* cursor) {
    int i = threadIdx.x;
    if (i < E_NUM) { counts[i] = 0; cursor[i] = 0; }
}

// ---------------------------------------------------------------- router
// softmax over 8 logits, top-2, renormalize. One thread per token.
__global__ void router_kernel(const float* __restrict__ gating,
                              int* __restrict__ expert_id,
                              float* __restrict__ wt,
                              int* __restrict__ counts) {
    int t = blockIdx.x * blockDim.x + threadIdx.x;
    if (t >= T_TOK) return;
    float l[E_NUM];
    float m = -1e30f;
    #pragma unroll
    for (int e = 0; e < E_NUM; e++) { l[e] = gating[t * E_NUM + e]; m = fmaxf(m, l[e]); }
    float p[E_NUM];
    #pragma unroll
    for (int e = 0; e < E_NUM; e++) p[e] = __expf(l[e] - m);
    // argmax (first max wins, like jax top_k tie order)
    int i0 = 0; float p0 = p[0];
    #pragma unroll
    for (int e = 1; e < E_NUM; e++) if (p[e] > p0) { p0 = p[e]; i0 = e; }
    int i1 = -1; float p1 = -1.f;
    #pragma unroll
    for (int e = 0; e < E_NUM; e++) if (e != i0 && p[e] > p1) { p1 = p[e]; i1 = e; }
    float inv = 1.f / (p0 + p1);
    expert_id[t * 2 + 0] = i0; wt[t * 2 + 0] = p0 * inv;
    expert_id[t * 2 + 1] = i1; wt[t * 2 + 1] = p1 * inv;
    atomicAdd(&counts[i0], 1);
    atomicAdd(&counts[i1], 1);
}

// ---------------------------------------------------------------- scan + tile map
__global__ void scan_kernel(const int* __restrict__ counts,
                            int* __restrict__ offsets,
                            int* __restrict__ tile_e, int* __restrict__ tile_m0,
                            int* __restrict__ n_slots) {
    if (threadIdx.x != 0 || blockIdx.x != 0) return;
    int off = 0;
    for (int e = 0; e < E_NUM; e++) { offsets[e] = off; off += counts[e]; }
    offsets[E_NUM] = off;
    int s = 0;
    for (int e = 0; e < E_NUM; e++)
        for (int m0 = offsets[e]; m0 < offsets[e + 1]; m0 += 128) {
            tile_e[s] = e; tile_m0[s] = m0; s++;
        }
    *n_slots = s;
}

// ---------------------------------------------------------------- scatter
// Order within an expert group is atomic-race-dependent, but every row's
// value is order-independent (row-local GEMM), and the final write goes to
// pair_dst -> bitwise deterministic output.
__global__ void scatter_kernel(const int* __restrict__ expert_id,
                               const float* __restrict__ wt,
                               const int* __restrict__ offsets,
                               int* __restrict__ cursor,
                               int* __restrict__ pair_token,
                               int* __restrict__ pair_dst,
                               float* __restrict__ pair_wt) {
    int t = blockIdx.x * blockDim.x + threadIdx.x;
    if (t >= T_TOK) return;
    #pragma unroll
    for (int k = 0; k < TOPK; k++) {
        int e = expert_id[t * 2 + k];
        int p = offsets[e] + atomicAdd(&cursor[e], 1);
        pair_token[p] = t;
        pair_dst[p]   = t * 2 + k;
        pair_wt[p]    = wt[t * 2 + k];
    }
}

// ---------------------------------------------------------------- GEMM1 + SwiGLU
// Block: 128 rows x 64 act-cols. B tile = 128 w1-rows: rows [0,64) = gate
// strip (w1 rows c0..c0+63), rows [64,128) = up strip (w1 rows 2048+c0..).
// 4 waves in 2x2: each wave owns 64 rows x 32 act cols (gate frags j=0,1
// pair lane-exactly with up frags j=2,3).
__global__ __launch_bounds__(256)
void gemm1_kernel(const float* __restrict__ hidden,
                  const float* __restrict__ w1,
                  const int* __restrict__ pair_token,
                  const int* __restrict__ offsets,
                  const int* __restrict__ tile_e,
                  const int* __restrict__ tile_m0,
                  const int* __restrict__ n_slots,
                  bf16_t* __restrict__ act) {
    int slot = blockIdx.x;
    if (slot >= *n_slots) return;
    int e    = tile_e[slot];
    int m0   = tile_m0[slot];
    int mend = offsets[e + 1];
    int c0   = blockIdx.y * 64;  // act cols [c0, c0+64)
    const float* w1e = w1 + (size_t)e * (2 * I_DIM) * H_DIM;

    __shared__ bf16_t lA[128][40];  // +8 pad -> 80B row stride, ~2-way conflicts
    __shared__ bf16_t lB[128][40];

    int tid = threadIdx.x;
    int r = tid >> 1, h = tid & 1;              // staging: 2 threads/row, 16 f32 each
    int tok = -1;
    if (m0 + r < mend) tok = pair_token[m0 + r];
    const float* aSrc = hidden + (size_t)(tok < 0 ? 0 : tok) * H_DIM + h * 16;
    int w1row = (r < 64) ? (c0 + r) : (I_DIM + c0 + (r - 64));
    const float* bSrc = w1e + (size_t)w1row * H_DIM + h * 16;

    int lane = tid & 63;
    int wid  = tid >> 6;
    int wm = wid >> 1, wn = wid & 1;
    int arow = wm * 64 + (lane & 15);
    int koff = (lane >> 4) * 8;

    f32x4 acc[4][4];
    #pragma unroll
    for (int i = 0; i < 4; i++)
        #pragma unroll
        for (int j = 0; j < 4; j++) acc[i][j] = zero4();

    for (int k0 = 0; k0 < H_DIM; k0 += 32) {
        __syncthreads();
        {   // stage A (gathered token rows), f32 -> bf16
            f32x4 v0 = zero4(), v1 = zero4(), v2 = zero4(), v3 = zero4();
            if (tok >= 0) {
                const f32x4* s = (const f32x4*)(aSrc + k0);
                v0 = s[0]; v1 = s[1]; v2 = s[2]; v3 = s[3];
            }
            bf16x8 o0, o1;
            #pragma unroll
            for (int j = 0; j < 4; j++) {
                o0[j] = (bf16_t)v0[j]; o0[4 + j] = (bf16_t)v1[j];
                o1[j] = (bf16_t)v2[j]; o1[4 + j] = (bf16_t)v3[j];
            }
            *(bf16x8*)&lA[r][h * 16]     = o0;
            *(bf16x8*)&lA[r][h * 16 + 8] = o1;
        }
        {   // stage B (w1 gate+up strips), f32 -> bf16
            const f32x4* s = (const f32x4*)(bSrc + k0);
            f32x4 v0 = s[0], v1 = s[1], v2 = s[2], v3 = s[3];
            bf16x8 o0, o1;
            #pragma unroll
            for (int j = 0; j < 4; j++) {
                o0[j] = (bf16_t)v0[j]; o0[4 + j] = (bf16_t)v1[j];
                o1[j] = (bf16_t)v2[j]; o1[4 + j] = (bf16_t)v3[j];
            }
            *(bf16x8*)&lB[r][h * 16]     = o0;
            *(bf16x8*)&lB[r][h * 16 + 8] = o1;
        }
        __syncthreads();

        bf16x8 a[4], b[4];
        #pragma unroll
        for (int i = 0; i < 4; i++) a[i] = *(const bf16x8*)&lA[arow + i * 16][koff];
        int brow = wn * 32 + (lane & 15);
        #pragma unroll
        for (int j = 0; j < 2; j++) b[j]     = *(const bf16x8*)&lB[brow + j * 16][koff];
        #pragma unroll
        for (int j = 0; j < 2; j++) b[2 + j] = *(const bf16x8*)&lB[64 + brow + j * 16][koff];
        #pragma unroll
        for (int i = 0; i < 4; i++)
            #pragma unroll
            for (int j = 0; j < 4; j++)
                acc[i][j] = __builtin_amdgcn_mfma_f32_16x16x32_bf16(a[i], b[j], acc[i][j], 0, 0, 0);
    }

    // epilogue: act = silu(gate) * up, store bf16
    int rbase = (lane >> 4) * 4;
    int colb  = c0 + wn * 32 + (lane & 15);
    #pragma unroll
    for (int i = 0; i < 4; i++) {
        #pragma unroll
        for (int j = 0; j < 2; j++) {
            f32x4 g = acc[i][j], u = acc[i][j + 2];
            #pragma unroll
            for (int rr = 0; rr < 4; rr++) {
                int m = m0 + wm * 64 + i * 16 + rbase + rr;
                if (m < mend) {
                    float gv = g[rr];
                    float sv = gv / (1.f + __expf(-gv));
                    act[(size_t)m * I_DIM + colb + j * 16] = (bf16_t)(sv * u[rr]);
                }
            }
        }
    }
}

// ---------------------------------------------------------------- GEMM2 (+ scale, scatter)
__global__ __launch_bounds__(256)
void gemm2_kernel(const bf16_t* __restrict__ act,
                  const float* __restrict__ w2,
                  const int* __restrict__ offsets,
                  const int* __restrict__ tile_e,
                  const int* __restrict__ tile_m0,
                  const int* __restrict__ n_slots,
                  const int* __restrict__ pair_dst,
                  const float* __restrict__ pair_wt,
                  float* __restrict__ ybuf) {
    int slot = blockIdx.x;
    if (slot >= *n_slots) return;
    int e    = tile_e[slot];
    int m0   = tile_m0[slot];
    int mend = offsets[e + 1];
    int n0   = blockIdx.y * 128;
    const float* w2e = w2 + (size_t)e * H_DIM * I_DIM;

    __shared__ bf16_t lA[128][40];
    __shared__ bf16_t lB[128][40];

    int tid = threadIdx.x;
    int r = tid >> 1, h = tid & 1;
    bool avalid = (m0 + r < mend);
    const bf16_t* aSrc = act + (size_t)(avalid ? (m0 + r) : 0) * I_DIM + h * 16;
    const float*  bSrc = w2e + (size_t)(n0 + r) * I_DIM + h * 16;

    int lane = tid & 63;
    int wid  = tid >> 6;
    int wm = wid >> 1, wn = wid & 1;
    int arow = wm * 64 + (lane & 15);
    int koff = (lane >> 4) * 8;

    f32x4 acc[4][4];
    #pragma unroll
    for (int i = 0; i < 4; i++)
        #pragma unroll
        for (int j = 0; j < 4; j++) acc[i][j] = zero4();

    for (int k0 = 0; k0 < I_DIM; k0 += 32) {
        __syncthreads();
        {   // stage A (already bf16)
            bf16x8 o0, o1;
            if (avalid) {
                o0 = *(const bf16x8*)(aSrc + k0);
                o1 = *(const bf16x8*)(aSrc + k0 + 8);
            } else {
                #pragma unroll
                for (int j = 0; j < 8; j++) { o0[j] = (bf16_t)0.f; o1[j] = (bf16_t)0.f; }
            }
            *(bf16x8*)&lA[r][h * 16]     = o0;
            *(bf16x8*)&lA[r][h * 16 + 8] = o1;
        }
        {   // stage B (w2, f32 -> bf16)
            const f32x4* s = (const f32x4*)(bSrc + k0);
            f32x4 v0 = s[0], v1 = s[1], v2 = s[2], v3 = s[3];
            bf16x8 o0, o1;
            #pragma unroll
            for (int j = 0; j < 4; j++) {
                o0[j] = (bf16_t)v0[j]; o0[4 + j] = (bf16_t)v1[j];
                o1[j] = (bf16_t)v2[j]; o1[4 + j] = (bf16_t)v3[j];
            }
            *(bf16x8*)&lB[r][h * 16]     = o0;
            *(bf16x8*)&lB[r][h * 16 + 8] = o1;
        }
        __syncthreads();

        bf16x8 a[4], b[4];
        #pragma unroll
        for (int i = 0; i < 4; i++) a[i] = *(const bf16x8*)&lA[arow + i * 16][koff];
        int brow = wn * 64 + (lane & 15);
        #pragma unroll
        for (int j = 0; j < 4; j++) b[j] = *(const bf16x8*)&lB[brow + j * 16][koff];
        #pragma unroll
        for (int i = 0; i < 4; i++)
            #pragma unroll
            for (int j = 0; j < 4; j++)
                acc[i][j] = __builtin_amdgcn_mfma_f32_16x16x32_bf16(a[i], b[j], acc[i][j], 0, 0, 0);
    }

    // epilogue: scale by gate weight, scatter to ybuf[pair_dst]
    int rbase = (lane >> 4) * 4;
    int colb  = n0 + wn * 64 + (lane & 15);
    #pragma unroll
    for (int i = 0; i < 4; i++) {
        #pragma unroll
        for (int rr = 0; rr < 4; rr++) {
            int m = m0 + wm * 64 + i * 16 + rbase + rr;
            if (m < mend) {
                int   dst = pair_dst[m];
                float w   = pair_wt[m];
                #pragma unroll
                for (int j = 0; j < 4; j++)
                    ybuf[(size_t)dst * H_DIM + colb + j * 16] = acc[i][j][rr] * w;
            }
        }
    }
}

// ---------------------------------------------------------------- combine
__global__ void combine_kernel(const float* __restrict__ ybuf,
                               float* __restrict__ out) {
    int idx = blockIdx.x * 256 + threadIdx.x;   // one float4 each
    int t = idx >> 8;                           // 256 float4 per token row
    int h = idx & 255;
    const f32x4* y0 = (const f32x4*)(ybuf + (size_t)(t * 2)     * H_DIM) + h;
    const f32x4* y1 = (const f32x4*)(ybuf + (size_t)(t * 2 + 1) * H_DIM) + h;
    f32x4 s = *y0 + *y1;
    ((f32x4*)out)[idx] = s;
}

// ---------------------------------------------------------------- launch
extern "C" void kernel_launch(void* const* d_in, const int* in_sizes, int n_in,
                              void* d_out, int out_size, void* d_ws, size_t ws_size,
                              hipStream_t stream) {
    const float* hidden = (const float*)d_in[0];
    const float* w1     = (const float*)d_in[1];
    const float* w2     = (const float*)d_in[2];
    const float* gating = (const float*)d_in[3];
    float* out = (float*)d_out;

    char* ws = (char*)d_ws;
    size_t off = 0;
    auto alloc = [&](size_t bytes) -> void* {
        void* p = ws + off;
        off += (bytes + 255) & ~(size_t)255;
        return p;
    };
    float*  ybuf       = (float*)alloc((size_t)P_MAX * H_DIM * sizeof(float));   // 16 MB
    bf16_t* act        = (bf16_t*)alloc((size_t)P_MAX * I_DIM * sizeof(bf16_t)); // 16 MB
    int*    expert_id  = (int*)alloc(P_MAX * sizeof(int));
    float*  wt         = (float*)alloc(P_MAX * sizeof(float));
    int*    pair_token = (int*)alloc(P_MAX * sizeof(int));
    int*    pair_dst   = (int*)alloc(P_MAX * sizeof(int));
    float*  pair_wt    = (float*)alloc(P_MAX * sizeof(float));
    int*    counts     = (int*)alloc(E_NUM * sizeof(int));
    int*    offsets    = (int*)alloc((E_NUM + 1) * sizeof(int));
    int*    cursor     = (int*)alloc(E_NUM * sizeof(int));
    int*    n_slots    = (int*)alloc(sizeof(int));
    int*    tile_e     = (int*)alloc(MAX_SLOTS * sizeof(int));
    int*    tile_m0    = (int*)alloc(MAX_SLOTS * sizeof(int));

    init_kernel<<<1, 64, 0, stream>>>(counts, cursor);
    router_kernel<<<(T_TOK + 255) / 256, 256, 0, stream>>>(gating, expert_id, wt, counts);
    scan_kernel<<<1, 1, 0, stream>>>(counts, offsets, tile_e, tile_m0, n_slots);
    scatter_kernel<<<(T_TOK + 255) / 256, 256, 0, stream>>>(expert_id, wt, offsets, cursor,
                                                            pair_token, pair_dst, pair_wt);
    gemm1_kernel<<<dim3(MAX_SLOTS, I_DIM / 64), 256, 0, stream>>>(
        hidden, w1, pair_token, offsets, tile_e, tile_m0, n_slots, act);
    gemm2_kernel<<<dim3(MAX_SLOTS, H_DIM / 128), 256, 0, stream>>>(
        act, w2, offsets, tile_e, tile_m0, n_slots, pair_dst, pair_wt, ybuf);
    combine_kernel<<<(T_TOK * H_DIM / 4) / 256, 256, 0, stream>>>(ybuf, out);

    (void)in_sizes; (void)n_in; (void)out_size; (void)ws_size;
}